// Round 8
// baseline (280.628 us; speedup 1.0000x reference)
//
#include <hip/hip_runtime.h>

#define N_NODES 50000
#define NFEAT 128
#define NEDGE 800000
#define NGRAPH 512
#define NCE 64
#define EPS 1e-5f
#define NBUCK 196            // ceil(50000/256) buckets of 256 nodes
#define EPB 4096             // edges per scatter block
#define NSCAT 196            // scatter blocks
#define CPB 64               // capacity per (bucket, block) cell: mean 21, +9 sigma
#define BCAP 6144            // per-bucket colidx capacity (avg 4082, sigma 64 -> +32 sigma)

typedef short s8v __attribute__((ext_vector_type(8)));
typedef float f4v __attribute__((ext_vector_type(4)));

// ---------- bf16 helpers (manual, bit-exact RNE) ----------
static __device__ __forceinline__ unsigned short f2bf(float f) {
    unsigned int u = __float_as_uint(f);
    unsigned int r = u + 0x7fffu + ((u >> 16) & 1u);
    return (unsigned short)(r >> 16);
}
static __device__ __forceinline__ float bf_lo(unsigned int packed) {
    return __uint_as_float(packed << 16);
}
static __device__ __forceinline__ float bf_hi(unsigned int packed) {
    return __uint_as_float(packed & 0xffff0000u);
}
static __device__ __forceinline__ float bf_us(unsigned short us) {
    return __uint_as_float(((unsigned int)us) << 16);
}

// ---------- 1. scatter + wcast fused (no global atomics, no init ordering) ----------
// blocks 0..NSCAT-1: partition EPB edges into recbuf[b][blk][CPB] + cnts[blk][b]
// blocks NSCAT..NSCAT+127: cast/transpose W1/W2 to bf16 WT
__global__ __launch_bounds__(256) void scatter_wcast_kernel(
    const int* __restrict__ ei,
    const float* __restrict__ W1, const float* __restrict__ W2,
    unsigned short* __restrict__ WT1, unsigned short* __restrict__ WT2,
    unsigned int* __restrict__ recbuf, unsigned short* __restrict__ cnts, int E)
{
    int bid = blockIdx.x;
    int tid = threadIdx.x;
    if (bid >= NSCAT) {
        int wb = bid - NSCAT;                    // 0..127
        const float* W = (wb & 1) ? W2 : W1;
        unsigned short* WT = (wb & 1) ? WT2 : WT1;
        int idx = (wb >> 1) * 256 + tid;         // 64 blocks x 256 = 16384 each
        int k = idx >> 7, nn = idx & 127;
        WT[nn * 128 + k] = f2bf(W[idx]);
        return;
    }
    __shared__ int hist[NBUCK];
    __shared__ int lbase[NBUCK];
    __shared__ int cur[NBUCK];
    __shared__ int scanbuf[256];
    __shared__ unsigned int staging[EPB];
    if (tid < NBUCK) { hist[tid] = 0; cur[tid] = 0; }
    __syncthreads();

    unsigned int rec[EPB / 256];
    int e0 = bid * EPB + tid;
#pragma unroll
    for (int i = 0; i < EPB / 256; ++i) {
        int e = e0 + i * 256;
        if (e < E) {
            unsigned int sv = (unsigned)ei[e];
            unsigned int dv = (unsigned)ei[E + e];
            rec[i] = sv | (dv << 16);
            atomicAdd(&hist[dv >> 8], 1);
        } else {
            rec[i] = 0xffffffffu;
        }
    }
    __syncthreads();
    int v = (tid < NBUCK) ? hist[tid] : 0;
    scanbuf[tid] = v; __syncthreads();
    for (int off = 1; off < 256; off <<= 1) {
        int t = (tid >= off) ? scanbuf[tid - off] : 0;
        __syncthreads();
        scanbuf[tid] += t;
        __syncthreads();
    }
    if (tid < NBUCK) lbase[tid] = scanbuf[tid] - v;
    int total = scanbuf[255];
    __syncthreads();
#pragma unroll
    for (int i = 0; i < EPB / 256; ++i) {
        if (rec[i] != 0xffffffffu) {
            int b = rec[i] >> 24;                // dst >> 8
            int loc = atomicAdd(&cur[b], 1);
            staging[lbase[b] + loc] = rec[i];
        }
    }
    __syncthreads();
    if (tid < NBUCK) cnts[bid * NBUCK + tid] = (unsigned short)min(v, CPB);
    for (int s = tid; s < total; s += 256) {
        unsigned int r = staging[s];
        int b = r >> 24;
        int pos = s - lbase[b];
        if (pos < CPB)
            recbuf[((size_t)b * NSCAT + bid) * CPB + pos] = r;
    }
}

// ---------- 2. per-bucket CSR finalize ----------
__global__ __launch_bounds__(256) void bucket_csr_kernel(
    const unsigned int* __restrict__ recbuf, const unsigned short* __restrict__ cnts,
    int* __restrict__ rowbeg, unsigned short* __restrict__ deg,
    float* __restrict__ dinv, unsigned short* __restrict__ colidx)
{
    __shared__ int cnt[256];
    __shared__ int cur[256];
    __shared__ int scanbuf[256];
    __shared__ unsigned short stage[BCAP];
    int b = blockIdx.x, tid = threadIdx.x;
    const unsigned int* rb = recbuf + (size_t)b * NSCAT * CPB;
    cnt[tid] = 0;
    __syncthreads();
    // pass 1: per-node counts
    for (int s = tid; s < NSCAT * CPB; s += 256) {
        int blk = s >> 6;                         // CPB = 64
        int pos = s & 63;
        int c = (int)cnts[blk * NBUCK + b];       // wave-uniform
        if (pos < c) {
            unsigned int r = rb[s];
            atomicAdd(&cnt[(r >> 16) & 255], 1);
        }
    }
    __syncthreads();
    int v = cnt[tid];
    scanbuf[tid] = v; __syncthreads();
    for (int off = 1; off < 256; off <<= 1) {
        int t = (tid >= off) ? scanbuf[tid - off] : 0;
        __syncthreads();
        scanbuf[tid] += t;
        __syncthreads();
    }
    int excl = scanbuf[tid] - v;
    int len = scanbuf[255];
    int node = b * 256 + tid;
    if (node < N_NODES) {
        rowbeg[node] = b * BCAP + excl;
        deg[node] = (unsigned short)v;
        dinv[node] = rsqrtf((float)v + 1.0f);
    }
    cur[tid] = excl;
    __syncthreads();
    // pass 2: scatter src into LDS stage at final positions
    for (int s = tid; s < NSCAT * CPB; s += 256) {
        int blk = s >> 6;
        int pos = s & 63;
        int c = (int)cnts[blk * NBUCK + b];
        if (pos < c) {
            unsigned int r = rb[s];
            int p = atomicAdd(&cur[(r >> 16) & 255], 1);
            stage[p] = (unsigned short)(r & 0xffffu);
        }
    }
    __syncthreads();
    for (int s = tid; s < len; s += 256) colidx[b * BCAP + s] = stage[s];
}

// ---------- MFMA GEMM: HS[r][c] = bf16( (A @ W)[r][c] * dinv[r] ) ----------
template<bool FP32IN>
__global__ __launch_bounds__(256) void gemm_mfma_kernel(
    const void* __restrict__ Ain, const unsigned short* __restrict__ WTg,
    const float* __restrict__ dinv, unsigned short* __restrict__ HS, int nrows)
{
    __shared__ unsigned short as[128 * 128];   // 32 KB; reused for result staging
    __shared__ unsigned short wt[128 * 128];   // 32 KB
    const int tid = threadIdx.x;
    const int row0 = blockIdx.x * 128;

    {
        const uint4* src = reinterpret_cast<const uint4*>(WTg);
        uint4* dst = reinterpret_cast<uint4*>(wt);
#pragma unroll
        for (int i = 0; i < 8; ++i) dst[tid + i * 256] = src[tid + i * 256];
    }
    if (FP32IN) {
        const float* X = (const float*)Ain;
#pragma unroll
        for (int i = 0; i < 16; ++i) {
            int f = tid + i * 256;
            int r = f >> 5, c4 = f & 31;
            int rr = row0 + r; if (rr >= nrows) rr = nrows - 1;
            float4 v = *reinterpret_cast<const float4*>(&X[rr * 128 + c4 * 4]);
            ushort4 o;
            o.x = f2bf(v.x); o.y = f2bf(v.y); o.z = f2bf(v.z); o.w = f2bf(v.w);
            *reinterpret_cast<ushort4*>(&as[r * 128 + c4 * 4]) = o;
        }
    } else {
        const unsigned short* X = (const unsigned short*)Ain;
#pragma unroll
        for (int i = 0; i < 8; ++i) {
            int f = tid + i * 256;
            int r = f >> 4, c8 = f & 15;
            int rr = row0 + r; if (rr >= nrows) rr = nrows - 1;
            *reinterpret_cast<uint4*>(&as[r * 128 + c8 * 8]) =
                *reinterpret_cast<const uint4*>(&X[rr * 128 + c8 * 8]);
        }
    }
    __syncthreads();

    const int w = tid >> 6;
    const int lane = tid & 63;
    const int quad = lane >> 4;
    const int col0 = lane & 15;

    s8v afr[2][4];
#pragma unroll
    for (int rt = 0; rt < 2; ++rt)
#pragma unroll
        for (int kt = 0; kt < 4; ++kt)
            afr[rt][kt] = *reinterpret_cast<const s8v*>(
                &as[(w * 32 + rt * 16 + col0) * 128 + kt * 32 + quad * 8]);

    f4v acc[2][8];
#pragma unroll
    for (int rt = 0; rt < 2; ++rt)
#pragma unroll
        for (int nt = 0; nt < 8; ++nt)
            acc[rt][nt] = (f4v){0.f, 0.f, 0.f, 0.f};

#pragma unroll
    for (int nt = 0; nt < 8; ++nt) {
        s8v bfr[4];
#pragma unroll
        for (int kt = 0; kt < 4; ++kt)
            bfr[kt] = *reinterpret_cast<const s8v*>(
                &wt[(nt * 16 + col0) * 128 + kt * 32 + quad * 8]);
#pragma unroll
        for (int rt = 0; rt < 2; ++rt)
#pragma unroll
            for (int kt = 0; kt < 4; ++kt)
                acc[rt][nt] = __builtin_amdgcn_mfma_f32_16x16x32_bf16(
                    afr[rt][kt], bfr[kt], acc[rt][nt], 0, 0, 0);
    }

    float dv[2][4];
#pragma unroll
    for (int rt = 0; rt < 2; ++rt)
#pragma unroll
        for (int reg = 0; reg < 4; ++reg) {
            int r = row0 + w * 32 + rt * 16 + quad * 4 + reg;
            dv[rt][reg] = (r < nrows) ? dinv[r] : 0.f;
        }

#pragma unroll
    for (int rt = 0; rt < 2; ++rt)
#pragma unroll
        for (int nt = 0; nt < 8; ++nt)
#pragma unroll
            for (int reg = 0; reg < 4; ++reg) {
                int rl = w * 32 + rt * 16 + quad * 4 + reg;
                as[rl * 128 + nt * 16 + col0] = f2bf(acc[rt][nt][reg] * dv[rt][reg]);
            }
    __syncthreads();
#pragma unroll
    for (int i = 0; i < 8; ++i) {
        int f = tid + i * 256;
        int r = f >> 4, c8 = f & 15;
        if (row0 + r < nrows)
            *reinterpret_cast<uint4*>(&HS[(size_t)(row0 + r) * 128 + c8 * 8]) =
                *reinterpret_cast<const uint4*>(&as[r * 128 + c8 * 8]);
    }
}

// ---------- aggregation v4: QUAD-row gathers (16 B/lane, 4 rows per wave-load) ----------
// lane = qd*16+sub: quad qd handles rows u[4j+qd], sub covers features sub*8..sub*8+7.
// 8 loads in flight = 32 rows = 8 KB/wave. Self row folded in as neighbor 0.
static __device__ __forceinline__ void addrow(float* a, uint4 t) {
    a[0] += bf_lo(t.x); a[1] += bf_hi(t.x);
    a[2] += bf_lo(t.y); a[3] += bf_hi(t.y);
    a[4] += bf_lo(t.z); a[5] += bf_hi(t.z);
    a[6] += bf_lo(t.w); a[7] += bf_hi(t.w);
}
__global__ __launch_bounds__(256) void aggregate_kernel(
    const uint4* __restrict__ H4,                 // [N][16] uint4 (bf16x8)
    const int* __restrict__ rowbeg, const unsigned short* __restrict__ deg,
    const unsigned short* __restrict__ colidx,
    const float* __restrict__ dinv, const float* __restrict__ bias,
    uint4* __restrict__ OUT, int n)
{
    int wid = (blockIdx.x * blockDim.x + threadIdx.x) >> 6;
    int lane = threadIdx.x & 63;
    if (wid >= n) return;
    const int qd = lane >> 4;
    const int sub = lane & 15;
    int beg = rowbeg[wid];
    int cnt = (int)deg[wid] + 1;                  // + self
    float accA[8] = {0.f, 0.f, 0.f, 0.f, 0.f, 0.f, 0.f, 0.f};
    float accB[8] = {0.f, 0.f, 0.f, 0.f, 0.f, 0.f, 0.f, 0.f};
    for (int base = 0; base < cnt; base += 64) {
        int m = cnt - base; if (m > 64) m = 64;
        int p = base + lane;
        int idx = 0;
        if (lane < m) idx = (p == 0) ? wid : (int)colidx[beg + p - 1];
        int j = 0;
        for (; j + 32 <= m; j += 32) {            // 8 quad-loads = 32 rows in flight
            uint4 t[8];
#pragma unroll
            for (int q = 0; q < 8; ++q) {
                int u = __shfl(idx, j + q * 4 + qd);
                t[q] = H4[(size_t)u * 16 + sub];
            }
#pragma unroll
            for (int q = 0; q < 8; q += 2) {
                addrow(accA, t[q]);
                addrow(accB, t[q + 1]);
            }
        }
        for (; j + 8 <= m; j += 8) {              // 2 quad-loads
            int u0 = __shfl(idx, j + qd);
            int u1 = __shfl(idx, j + 4 + qd);
            uint4 t0 = H4[(size_t)u0 * 16 + sub];
            uint4 t1 = H4[(size_t)u1 * 16 + sub];
            addrow(accA, t0);
            addrow(accB, t1);
        }
        for (; j < m; j += 4) {                   // masked quad-load (<= 1 iter)
            int sl = j + qd;
            int u = __shfl(idx, sl < m ? sl : m - 1);
            uint4 t = H4[(size_t)u * 16 + sub];
            if (sl >= m) { t.x = 0u; t.y = 0u; t.z = 0u; t.w = 0u; }
            addrow(accA, t);
        }
    }
#pragma unroll
    for (int i = 0; i < 8; ++i) accA[i] += accB[i];
#pragma unroll
    for (int i = 0; i < 8; ++i) {
        accA[i] += __shfl_xor(accA[i], 16);
        accA[i] += __shfl_xor(accA[i], 32);
    }
    if (qd == 0) {
        float sc = dinv[wid];
        float4 bv0 = *reinterpret_cast<const float4*>(&bias[sub * 8]);
        float4 bv1 = *reinterpret_cast<const float4*>(&bias[sub * 8 + 4]);
        float o0 = fmaxf(fmaf(accA[0], sc, bv0.x), 0.f);
        float o1 = fmaxf(fmaf(accA[1], sc, bv0.y), 0.f);
        float o2 = fmaxf(fmaf(accA[2], sc, bv0.z), 0.f);
        float o3 = fmaxf(fmaf(accA[3], sc, bv0.w), 0.f);
        float o4 = fmaxf(fmaf(accA[4], sc, bv1.x), 0.f);
        float o5 = fmaxf(fmaf(accA[5], sc, bv1.y), 0.f);
        float o6 = fmaxf(fmaf(accA[6], sc, bv1.z), 0.f);
        float o7 = fmaxf(fmaf(accA[7], sc, bv1.w), 0.f);
        uint4 o;
        o.x = (unsigned int)f2bf(o0) | ((unsigned int)f2bf(o1) << 16);
        o.y = (unsigned int)f2bf(o2) | ((unsigned int)f2bf(o3) << 16);
        o.z = (unsigned int)f2bf(o4) | ((unsigned int)f2bf(o5) << 16);
        o.w = (unsigned int)f2bf(o6) | ((unsigned int)f2bf(o7) << 16);
        OUT[(size_t)wid * 16 + sub] = o;
    }
}

// ---------- fused pool + tail ----------
__global__ __launch_bounds__(256) void tail_kernel(
    const unsigned short* __restrict__ h2b, const int* __restrict__ batch,
    const int* __restrict__ cell, const float* __restrict__ emb,
    const float* __restrict__ Wc, const float* __restrict__ bc,
    const float* __restrict__ lncw, const float* __restrict__ lncb,
    const float* __restrict__ Wf1, const float* __restrict__ bf1,
    const float* __restrict__ ln1w, const float* __restrict__ ln1b,
    const float* __restrict__ Wf2, const float* __restrict__ bf2,
    float* __restrict__ out)
{
    __shared__ __align__(16) float comb[192];
    __shared__ __align__(16) float part[8][132];
    __shared__ float red[4];
    __shared__ __align__(16) float vec[128];
    const int gi = blockIdx.x;
    const int tid = threadIdx.x;
    const int cg = tid & 31;
    const int ks = tid >> 5;

    int lo = 0, hi = N_NODES;
    while (lo < hi) { int mid = (lo + hi) >> 1; if (batch[mid] < gi) lo = mid + 1; else hi = mid; }
    int lo2 = lo, hi2 = N_NODES;
    while (lo2 < hi2) { int mid = (lo2 + hi2) >> 1; if (batch[mid] < gi + 1) lo2 = mid + 1; else hi2 = mid; }

    {
        int half = tid >> 7;
        int j = tid & 127;
        float acc = 0.f;
        for (int v = lo + half; v < lo2; v += 2)
            acc += bf_us(h2b[(size_t)v * 128 + j]);
        part[half][j] = acc;
    }
    __syncthreads();
    if (tid < 128) comb[tid] = part[0][tid] + part[1][tid];
    else if (tid < 192) comb[tid] = emb[cell[gi] * 64 + (tid - 128)];
    __syncthreads();

    // ---- layer A: comb @ Wc ----
    {
        float c[24];
#pragma unroll
        for (int i = 0; i < 6; ++i) {
            float4 t = *reinterpret_cast<const float4*>(&comb[ks * 24 + i * 4]);
            c[i * 4 + 0] = t.x; c[i * 4 + 1] = t.y; c[i * 4 + 2] = t.z; c[i * 4 + 3] = t.w;
        }
        float a0 = 0.f, a1 = 0.f, a2 = 0.f, a3 = 0.f;
#pragma unroll
        for (int i = 0; i < 24; ++i) {
            const float4 w = *reinterpret_cast<const float4*>(&Wc[(ks * 24 + i) * 128 + cg * 4]);
            a0 = fmaf(c[i], w.x, a0);
            a1 = fmaf(c[i], w.y, a1);
            a2 = fmaf(c[i], w.z, a2);
            a3 = fmaf(c[i], w.w, a3);
        }
        float4 o; o.x = a0; o.y = a1; o.z = a2; o.w = a3;
        *reinterpret_cast<float4*>(&part[ks][cg * 4]) = o;
    }
    __syncthreads();
    {
        float y = 0.f;
        if (tid < 128) {
            y = bc[tid];
#pragma unroll
            for (int s = 0; s < 8; ++s) y += part[s][tid];
        }
        float s1 = (tid < 128) ? y : 0.f;
        float s2 = (tid < 128) ? y * y : 0.f;
        if (tid < 128) {
#pragma unroll
            for (int off = 32; off > 0; off >>= 1) {
                s1 += __shfl_down(s1, off);
                s2 += __shfl_down(s2, off);
            }
            if ((tid & 63) == 0) { red[(tid >> 6) * 2] = s1; red[(tid >> 6) * 2 + 1] = s2; }
        }
        __syncthreads();
        float mu = (red[0] + red[2]) * (1.f / 128.f);
        float ms = (red[1] + red[3]) * (1.f / 128.f);
        float var = ms - mu * mu;
        if (tid < 128) {
            float yv = (y - mu) * rsqrtf(var + EPS) * lncw[tid] + lncb[tid];
            vec[tid] = fmaxf(yv, 0.f);
        }
    }
    __syncthreads();

    // ---- layer B: vec @ Wf1, relu, LN ----
    {
        float c[16];
#pragma unroll
        for (int i = 0; i < 4; ++i) {
            float4 t = *reinterpret_cast<const float4*>(&vec[ks * 16 + i * 4]);
            c[i * 4 + 0] = t.x; c[i * 4 + 1] = t.y; c[i * 4 + 2] = t.z; c[i * 4 + 3] = t.w;
        }
        float a0 = 0.f, a1 = 0.f, a2 = 0.f, a3 = 0.f;
#pragma unroll
        for (int i = 0; i < 16; ++i) {
            const float4 w = *reinterpret_cast<const float4*>(&Wf1[(ks * 16 + i) * 128 + cg * 4]);
            a0 = fmaf(c[i], w.x, a0);
            a1 = fmaf(c[i], w.y, a1);
            a2 = fmaf(c[i], w.z, a2);
            a3 = fmaf(c[i], w.w, a3);
        }
        float4 o; o.x = a0; o.y = a1; o.z = a2; o.w = a3;
        *reinterpret_cast<float4*>(&part[ks][cg * 4]) = o;
    }
    __syncthreads();
    {
        float y = 0.f;
        if (tid < 128) {
            y = bf1[tid];
#pragma unroll
            for (int s = 0; s < 8; ++s) y += part[s][tid];
            y = fmaxf(y, 0.f);                 // relu BEFORE LN
        }
        float s1 = (tid < 128) ? y : 0.f;
        float s2 = (tid < 128) ? y * y : 0.f;
        if (tid < 128) {
#pragma unroll
            for (int off = 32; off > 0; off >>= 1) {
                s1 += __shfl_down(s1, off);
                s2 += __shfl_down(s2, off);
            }
            if ((tid & 63) == 0) { red[(tid >> 6) * 2] = s1; red[(tid >> 6) * 2 + 1] = s2; }
        }
        __syncthreads();
        float mu = (red[0] + red[2]) * (1.f / 128.f);
        float ms = (red[1] + red[3]) * (1.f / 128.f);
        float var = ms - mu * mu;
        if (tid < 128)
            vec[tid] = (y - mu) * rsqrtf(var + EPS) * ln1w[tid] + ln1b[tid];   // no relu
    }
    __syncthreads();

    // ---- layer C: vec @ Wf2 ----
    {
        float c[16];
#pragma unroll
        for (int i = 0; i < 4; ++i) {
            float4 t = *reinterpret_cast<const float4*>(&vec[ks * 16 + i * 4]);
            c[i * 4 + 0] = t.x; c[i * 4 + 1] = t.y; c[i * 4 + 2] = t.z; c[i * 4 + 3] = t.w;
        }
        float a0 = 0.f, a1 = 0.f, a2 = 0.f, a3 = 0.f;
#pragma unroll
        for (int i = 0; i < 16; ++i) {
            const float4 w = *reinterpret_cast<const float4*>(&Wf2[(ks * 16 + i) * 128 + cg * 4]);
            a0 = fmaf(c[i], w.x, a0);
            a1 = fmaf(c[i], w.y, a1);
            a2 = fmaf(c[i], w.z, a2);
            a3 = fmaf(c[i], w.w, a3);
        }
        float4 o; o.x = a0; o.y = a1; o.z = a2; o.w = a3;
        *reinterpret_cast<float4*>(&part[ks][cg * 4]) = o;
    }
    __syncthreads();
    if (tid < 128) {
        float y = bf2[tid];
#pragma unroll
        for (int s = 0; s < 8; ++s) y += part[s][tid];
        out[gi * 128 + tid] = y;
    }
}

// ---------- host launch ----------
extern "C" void kernel_launch(void* const* d_in, const int* in_sizes, int n_in,
                              void* d_out, int out_size, void* d_ws, size_t ws_size,
                              hipStream_t stream) {
    const float* x    = (const float*)d_in[0];
    const int*   ei   = (const int*)d_in[1];
    const int*   batch= (const int*)d_in[2];
    const int*   cell = (const int*)d_in[3];
    const float* W1   = (const float*)d_in[4];
    const float* b1   = (const float*)d_in[5];
    const float* W2   = (const float*)d_in[6];
    const float* b2   = (const float*)d_in[7];
    const float* emb  = (const float*)d_in[8];
    const float* Wc   = (const float*)d_in[9];
    const float* bc   = (const float*)d_in[10];
    const float* lncw = (const float*)d_in[11];
    const float* lncb = (const float*)d_in[12];
    const float* Wf1  = (const float*)d_in[13];
    const float* bf1  = (const float*)d_in[14];
    const float* ln1w = (const float*)d_in[15];
    const float* ln1b = (const float*)d_in[16];
    const float* Wf2  = (const float*)d_in[17];
    const float* bf2  = (const float*)d_in[18];
    float* out = (float*)d_out;

    char* ws = (char*)d_ws;
    size_t off = 0;
    auto alloc = [&](size_t bytes) { char* p = ws + off; off = (off + bytes + 255) & ~size_t(255); return p; };
    float*          dinv   = (float*)alloc(N_NODES * 4);
    int*            rowbeg = (int*)  alloc(N_NODES * 4);
    unsigned short* deg    = (unsigned short*)alloc(N_NODES * 2);
    unsigned short* colidx = (unsigned short*)alloc((size_t)NBUCK * BCAP * 2);
    unsigned int*   recbuf = (unsigned int*)alloc((size_t)NBUCK * NSCAT * CPB * 4);
    unsigned short* cnts   = (unsigned short*)alloc((size_t)NSCAT * NBUCK * 2);
    unsigned short* wt1    = (unsigned short*)alloc(128 * 128 * 2);
    unsigned short* wt2    = (unsigned short*)alloc(128 * 128 * 2);
    unsigned short* hs     = (unsigned short*)alloc((size_t)N_NODES * 128 * 2);
    unsigned short* h1     = (unsigned short*)alloc((size_t)N_NODES * 128 * 2);
    unsigned short* h2b    = (unsigned short*)alloc((size_t)N_NODES * 128 * 2);

    const int nbGemm = (N_NODES + 127) / 128;          // 391
    const int nbAgg  = (N_NODES + 3) / 4;              // 12500

    // 1. scatter + wcast (196 scatter blocks + 128 wcast blocks)
    scatter_wcast_kernel<<<NSCAT + 128, 256, 0, stream>>>(ei, W1, W2, wt1, wt2,
                                                          recbuf, cnts, NEDGE);
    // 2. CSR finalize
    bucket_csr_kernel<<<NBUCK, 256, 0, stream>>>(recbuf, cnts, rowbeg, deg, dinv, colidx);

    // conv1
    gemm_mfma_kernel<true><<<nbGemm, 256, 0, stream>>>(x, wt1, dinv, hs, N_NODES);
    aggregate_kernel<<<nbAgg, 256, 0, stream>>>((const uint4*)hs, rowbeg, deg, colidx,
                                                dinv, b1, (uint4*)h1, N_NODES);
    // conv2
    gemm_mfma_kernel<false><<<nbGemm, 256, 0, stream>>>(h1, wt2, dinv, hs, N_NODES);
    aggregate_kernel<<<nbAgg, 256, 0, stream>>>((const uint4*)hs, rowbeg, deg, colidx,
                                                dinv, b2, (uint4*)h2b, N_NODES);
    // fused pool + tail
    tail_kernel<<<NGRAPH, 256, 0, stream>>>(h2b, batch, cell, emb, Wc, bc, lncw, lncb,
                                            Wf1, bf1, ln1w, ln1b, Wf2, bf2, out);
}

// Round 9
// 259.712 us; speedup vs baseline: 1.0805x; 1.0805x over previous
//
#include <hip/hip_runtime.h>

#define N_NODES 50000
#define NFEAT 128
#define NEDGE 800000
#define NGRAPH 512
#define NCE 64
#define EPS 1e-5f
#define NBUCK 196            // ceil(50000/256) buckets of 256 nodes
#define EPB 4096             // edges per bucket_scatter block
#define BCAP 6144            // fixed per-bucket capacity (avg 4082, sigma 64 -> +32 sigma)

typedef short s8v __attribute__((ext_vector_type(8)));
typedef float f4v __attribute__((ext_vector_type(4)));

// ---------- bf16 helpers (manual, bit-exact RNE) ----------
static __device__ __forceinline__ unsigned short f2bf(float f) {
    unsigned int u = __float_as_uint(f);
    unsigned int r = u + 0x7fffu + ((u >> 16) & 1u);
    return (unsigned short)(r >> 16);
}
static __device__ __forceinline__ float bf_lo(unsigned int packed) {
    return __uint_as_float(packed << 16);
}
static __device__ __forceinline__ float bf_hi(unsigned int packed) {
    return __uint_as_float(packed & 0xffff0000u);
}
static __device__ __forceinline__ float bf_us(unsigned short us) {
    return __uint_as_float(((unsigned int)us) << 16);
}

// ---------- 0. weight cast+transpose + cursor init ----------
__global__ __launch_bounds__(256) void wcast_kernel(
    const float* __restrict__ W1, const float* __restrict__ W2,
    unsigned short* __restrict__ WT1, unsigned short* __restrict__ WT2,
    int* __restrict__ bucketCursor)
{
    if (blockIdx.x == 0 && blockIdx.y == 0 && threadIdx.x < NBUCK)
        bucketCursor[threadIdx.x] = 0;
    const float* W = blockIdx.y ? W2 : W1;
    unsigned short* WT = blockIdx.y ? WT2 : WT1;
    int idx = blockIdx.x * 256 + threadIdx.x;   // 64 blocks x 256 = 16384
    int k = idx >> 7, n = idx & 127;
    WT[n * 128 + k] = f2bf(W[idx]);
}

// ---------- 1. bucket scatter: packed records, atomic-cursor dense buckets ----------
__global__ __launch_bounds__(256) void bucket_scatter_kernel(
    const int* __restrict__ ei, int* __restrict__ bucketCursor,
    unsigned int* __restrict__ recbuf, int E)
{
    __shared__ int hist[NBUCK];
    __shared__ int lbase[NBUCK];
    __shared__ int gbase[NBUCK];
    __shared__ int cur[NBUCK];
    __shared__ int scanbuf[256];
    __shared__ unsigned int staging[EPB];
    int tid = threadIdx.x;
    if (tid < NBUCK) { hist[tid] = 0; cur[tid] = 0; }
    __syncthreads();

    unsigned int rec[EPB / 256];
    int e0 = blockIdx.x * EPB + tid;
#pragma unroll
    for (int i = 0; i < EPB / 256; ++i) {
        int e = e0 + i * 256;
        if (e < E) {
            unsigned int sv = (unsigned)ei[e];
            unsigned int dv = (unsigned)ei[E + e];
            rec[i] = sv | (dv << 16);
            atomicAdd(&hist[dv >> 8], 1);
        } else {
            rec[i] = 0xffffffffu;
        }
    }
    __syncthreads();
    int v = (tid < NBUCK) ? hist[tid] : 0;
    scanbuf[tid] = v; __syncthreads();
    for (int off = 1; off < 256; off <<= 1) {
        int t = (tid >= off) ? scanbuf[tid - off] : 0;
        __syncthreads();
        scanbuf[tid] += t;
        __syncthreads();
    }
    if (tid < NBUCK) lbase[tid] = scanbuf[tid] - v;
    int total = scanbuf[255];
    if (tid < NBUCK) gbase[tid] = (v > 0) ? atomicAdd(&bucketCursor[tid], v) : 0;
    __syncthreads();
#pragma unroll
    for (int i = 0; i < EPB / 256; ++i) {
        if (rec[i] != 0xffffffffu) {
            int b = rec[i] >> 24;       // dst >> 8
            int loc = atomicAdd(&cur[b], 1);
            staging[lbase[b] + loc] = rec[i];
        }
    }
    __syncthreads();
    for (int s = tid; s < total; s += 256) {
        unsigned int r = staging[s];
        int b = r >> 24;
        int pos = gbase[b] + (s - lbase[b]);
        if (pos < BCAP) recbuf[(size_t)b * BCAP + pos] = r;
    }
}

// ---------- 2. per-bucket CSR finalize (dense buckets) ----------
__global__ __launch_bounds__(256) void bucket_csr_kernel(
    const unsigned int* __restrict__ recbuf, const int* __restrict__ bucketCursor,
    int* __restrict__ rowbeg, unsigned short* __restrict__ deg,
    float* __restrict__ dinv, unsigned short* __restrict__ colidx)
{
    __shared__ int cnt[256];
    __shared__ int cur[256];
    __shared__ int scanbuf[256];
    __shared__ unsigned short stage[BCAP];
    int b = blockIdx.x, tid = threadIdx.x;
    int base = b * BCAP;
    int len = bucketCursor[b]; if (len > BCAP) len = BCAP;
    cnt[tid] = 0;
    __syncthreads();
    for (int s = tid; s < len; s += 256) {
        unsigned int r = recbuf[base + s];
        atomicAdd(&cnt[(r >> 16) & 255], 1);
    }
    __syncthreads();
    int v = cnt[tid];
    scanbuf[tid] = v; __syncthreads();
    for (int off = 1; off < 256; off <<= 1) {
        int t = (tid >= off) ? scanbuf[tid - off] : 0;
        __syncthreads();
        scanbuf[tid] += t;
        __syncthreads();
    }
    int excl = scanbuf[tid] - v;
    int node = b * 256 + tid;
    if (node < N_NODES) {
        rowbeg[node] = base + excl;
        deg[node] = (unsigned short)v;
        dinv[node] = rsqrtf((float)v + 1.0f);
    }
    cur[tid] = excl;
    __syncthreads();
    for (int s = tid; s < len; s += 256) {
        unsigned int r = recbuf[base + s];
        int pos = atomicAdd(&cur[(r >> 16) & 255], 1);
        stage[pos] = (unsigned short)(r & 0xffffu);
    }
    __syncthreads();
    for (int s = tid; s < len; s += 256) colidx[base + s] = stage[s];
}

// ---------- MFMA GEMM: HS[r][c] = bf16( (A @ W)[r][c] * dinv[r] ) ----------
template<bool FP32IN>
__global__ __launch_bounds__(256) void gemm_mfma_kernel(
    const void* __restrict__ Ain, const unsigned short* __restrict__ WTg,
    const float* __restrict__ dinv, unsigned short* __restrict__ HS, int nrows)
{
    __shared__ unsigned short as[128 * 128];   // 32 KB; reused for result staging
    __shared__ unsigned short wt[128 * 128];   // 32 KB
    const int tid = threadIdx.x;
    const int row0 = blockIdx.x * 128;

    {
        const uint4* src = reinterpret_cast<const uint4*>(WTg);
        uint4* dst = reinterpret_cast<uint4*>(wt);
#pragma unroll
        for (int i = 0; i < 8; ++i) dst[tid + i * 256] = src[tid + i * 256];
    }
    if (FP32IN) {
        const float* X = (const float*)Ain;
#pragma unroll
        for (int i = 0; i < 16; ++i) {
            int f = tid + i * 256;
            int r = f >> 5, c4 = f & 31;
            int rr = row0 + r; if (rr >= nrows) rr = nrows - 1;
            float4 v = *reinterpret_cast<const float4*>(&X[rr * 128 + c4 * 4]);
            ushort4 o;
            o.x = f2bf(v.x); o.y = f2bf(v.y); o.z = f2bf(v.z); o.w = f2bf(v.w);
            *reinterpret_cast<ushort4*>(&as[r * 128 + c4 * 4]) = o;
        }
    } else {
        const unsigned short* X = (const unsigned short*)Ain;
#pragma unroll
        for (int i = 0; i < 8; ++i) {
            int f = tid + i * 256;
            int r = f >> 4, c8 = f & 15;
            int rr = row0 + r; if (rr >= nrows) rr = nrows - 1;
            *reinterpret_cast<uint4*>(&as[r * 128 + c8 * 8]) =
                *reinterpret_cast<const uint4*>(&X[rr * 128 + c8 * 8]);
        }
    }
    __syncthreads();

    const int w = tid >> 6;
    const int lane = tid & 63;
    const int quad = lane >> 4;
    const int col0 = lane & 15;

    s8v afr[2][4];
#pragma unroll
    for (int rt = 0; rt < 2; ++rt)
#pragma unroll
        for (int kt = 0; kt < 4; ++kt)
            afr[rt][kt] = *reinterpret_cast<const s8v*>(
                &as[(w * 32 + rt * 16 + col0) * 128 + kt * 32 + quad * 8]);

    f4v acc[2][8];
#pragma unroll
    for (int rt = 0; rt < 2; ++rt)
#pragma unroll
        for (int nt = 0; nt < 8; ++nt)
            acc[rt][nt] = (f4v){0.f, 0.f, 0.f, 0.f};

#pragma unroll
    for (int nt = 0; nt < 8; ++nt) {
        s8v bfr[4];
#pragma unroll
        for (int kt = 0; kt < 4; ++kt)
            bfr[kt] = *reinterpret_cast<const s8v*>(
                &wt[(nt * 16 + col0) * 128 + kt * 32 + quad * 8]);
#pragma unroll
        for (int rt = 0; rt < 2; ++rt)
#pragma unroll
            for (int kt = 0; kt < 4; ++kt)
                acc[rt][nt] = __builtin_amdgcn_mfma_f32_16x16x32_bf16(
                    afr[rt][kt], bfr[kt], acc[rt][nt], 0, 0, 0);
    }

    float dv[2][4];
#pragma unroll
    for (int rt = 0; rt < 2; ++rt)
#pragma unroll
        for (int reg = 0; reg < 4; ++reg) {
            int r = row0 + w * 32 + rt * 16 + quad * 4 + reg;
            dv[rt][reg] = (r < nrows) ? dinv[r] : 0.f;
        }

#pragma unroll
    for (int rt = 0; rt < 2; ++rt)
#pragma unroll
        for (int nt = 0; nt < 8; ++nt)
#pragma unroll
            for (int reg = 0; reg < 4; ++reg) {
                int rl = w * 32 + rt * 16 + quad * 4 + reg;
                as[rl * 128 + nt * 16 + col0] = f2bf(acc[rt][nt][reg] * dv[rt][reg]);
            }
    __syncthreads();
#pragma unroll
    for (int i = 0; i < 8; ++i) {
        int f = tid + i * 256;
        int r = f >> 4, c8 = f & 15;
        if (row0 + r < nrows)
            *reinterpret_cast<uint4*>(&HS[(size_t)(row0 + r) * 128 + c8 * 8]) =
                *reinterpret_cast<const uint4*>(&as[r * 128 + c8 * 8]);
    }
}

// ---------- aggregation v4: QUAD-row gathers (16 B/lane, 4 rows per wave-load) ----------
static __device__ __forceinline__ void addrow(float* a, uint4 t) {
    a[0] += bf_lo(t.x); a[1] += bf_hi(t.x);
    a[2] += bf_lo(t.y); a[3] += bf_hi(t.y);
    a[4] += bf_lo(t.z); a[5] += bf_hi(t.z);
    a[6] += bf_lo(t.w); a[7] += bf_hi(t.w);
}
__global__ __launch_bounds__(256) void aggregate_kernel(
    const uint4* __restrict__ H4,                 // [N][16] uint4 (bf16x8)
    const int* __restrict__ rowbeg, const unsigned short* __restrict__ deg,
    const unsigned short* __restrict__ colidx,
    const float* __restrict__ dinv, const float* __restrict__ bias,
    uint4* __restrict__ OUT, int n)
{
    int wid = (blockIdx.x * blockDim.x + threadIdx.x) >> 6;
    int lane = threadIdx.x & 63;
    if (wid >= n) return;
    const int qd = lane >> 4;
    const int sub = lane & 15;
    int beg = rowbeg[wid];
    int cnt = (int)deg[wid] + 1;                  // + self
    float accA[8] = {0.f, 0.f, 0.f, 0.f, 0.f, 0.f, 0.f, 0.f};
    float accB[8] = {0.f, 0.f, 0.f, 0.f, 0.f, 0.f, 0.f, 0.f};
    for (int base = 0; base < cnt; base += 64) {
        int m = cnt - base; if (m > 64) m = 64;
        int p = base + lane;
        int idx = 0;
        if (lane < m) idx = (p == 0) ? wid : (int)colidx[beg + p - 1];
        int j = 0;
        for (; j + 32 <= m; j += 32) {            // 8 quad-loads = 32 rows in flight
            uint4 t[8];
#pragma unroll
            for (int q = 0; q < 8; ++q) {
                int u = __shfl(idx, j + q * 4 + qd);
                t[q] = H4[(size_t)u * 16 + sub];
            }
#pragma unroll
            for (int q = 0; q < 8; q += 2) {
                addrow(accA, t[q]);
                addrow(accB, t[q + 1]);
            }
        }
        for (; j + 8 <= m; j += 8) {              // 2 quad-loads
            int u0 = __shfl(idx, j + qd);
            int u1 = __shfl(idx, j + 4 + qd);
            uint4 t0 = H4[(size_t)u0 * 16 + sub];
            uint4 t1 = H4[(size_t)u1 * 16 + sub];
            addrow(accA, t0);
            addrow(accB, t1);
        }
        for (; j < m; j += 4) {                   // masked quad-load (<= 1 iter)
            int sl = j + qd;
            int u = __shfl(idx, sl < m ? sl : m - 1);
            uint4 t = H4[(size_t)u * 16 + sub];
            if (sl >= m) { t.x = 0u; t.y = 0u; t.z = 0u; t.w = 0u; }
            addrow(accA, t);
        }
    }
#pragma unroll
    for (int i = 0; i < 8; ++i) accA[i] += accB[i];
#pragma unroll
    for (int i = 0; i < 8; ++i) {
        accA[i] += __shfl_xor(accA[i], 16);
        accA[i] += __shfl_xor(accA[i], 32);
    }
    if (qd == 0) {
        float sc = dinv[wid];
        float4 bv0 = *reinterpret_cast<const float4*>(&bias[sub * 8]);
        float4 bv1 = *reinterpret_cast<const float4*>(&bias[sub * 8 + 4]);
        float o0 = fmaxf(fmaf(accA[0], sc, bv0.x), 0.f);
        float o1 = fmaxf(fmaf(accA[1], sc, bv0.y), 0.f);
        float o2 = fmaxf(fmaf(accA[2], sc, bv0.z), 0.f);
        float o3 = fmaxf(fmaf(accA[3], sc, bv0.w), 0.f);
        float o4 = fmaxf(fmaf(accA[4], sc, bv1.x), 0.f);
        float o5 = fmaxf(fmaf(accA[5], sc, bv1.y), 0.f);
        float o6 = fmaxf(fmaf(accA[6], sc, bv1.z), 0.f);
        float o7 = fmaxf(fmaf(accA[7], sc, bv1.w), 0.f);
        uint4 o;
        o.x = (unsigned int)f2bf(o0) | ((unsigned int)f2bf(o1) << 16);
        o.y = (unsigned int)f2bf(o2) | ((unsigned int)f2bf(o3) << 16);
        o.z = (unsigned int)f2bf(o4) | ((unsigned int)f2bf(o5) << 16);
        o.w = (unsigned int)f2bf(o6) | ((unsigned int)f2bf(o7) << 16);
        OUT[(size_t)wid * 16 + sub] = o;
    }
}

// ---------- fused pool + tail ----------
__global__ __launch_bounds__(256) void tail_kernel(
    const unsigned short* __restrict__ h2b, const int* __restrict__ batch,
    const int* __restrict__ cell, const float* __restrict__ emb,
    const float* __restrict__ Wc, const float* __restrict__ bc,
    const float* __restrict__ lncw, const float* __restrict__ lncb,
    const float* __restrict__ Wf1, const float* __restrict__ bf1,
    const float* __restrict__ ln1w, const float* __restrict__ ln1b,
    const float* __restrict__ Wf2, const float* __restrict__ bf2,
    float* __restrict__ out)
{
    __shared__ __align__(16) float comb[192];
    __shared__ __align__(16) float part[8][132];
    __shared__ float red[4];
    __shared__ __align__(16) float vec[128];
    const int gi = blockIdx.x;
    const int tid = threadIdx.x;
    const int cg = tid & 31;
    const int ks = tid >> 5;

    int lo = 0, hi = N_NODES;
    while (lo < hi) { int mid = (lo + hi) >> 1; if (batch[mid] < gi) lo = mid + 1; else hi = mid; }
    int lo2 = lo, hi2 = N_NODES;
    while (lo2 < hi2) { int mid = (lo2 + hi2) >> 1; if (batch[mid] < gi + 1) lo2 = mid + 1; else hi2 = mid; }

    {
        int half = tid >> 7;
        int j = tid & 127;
        float acc = 0.f;
        for (int v = lo + half; v < lo2; v += 2)
            acc += bf_us(h2b[(size_t)v * 128 + j]);
        part[half][j] = acc;
    }
    __syncthreads();
    if (tid < 128) comb[tid] = part[0][tid] + part[1][tid];
    else if (tid < 192) comb[tid] = emb[cell[gi] * 64 + (tid - 128)];
    __syncthreads();

    // ---- layer A: comb @ Wc ----
    {
        float c[24];
#pragma unroll
        for (int i = 0; i < 6; ++i) {
            float4 t = *reinterpret_cast<const float4*>(&comb[ks * 24 + i * 4]);
            c[i * 4 + 0] = t.x; c[i * 4 + 1] = t.y; c[i * 4 + 2] = t.z; c[i * 4 + 3] = t.w;
        }
        float a0 = 0.f, a1 = 0.f, a2 = 0.f, a3 = 0.f;
#pragma unroll
        for (int i = 0; i < 24; ++i) {
            const float4 w = *reinterpret_cast<const float4*>(&Wc[(ks * 24 + i) * 128 + cg * 4]);
            a0 = fmaf(c[i], w.x, a0);
            a1 = fmaf(c[i], w.y, a1);
            a2 = fmaf(c[i], w.z, a2);
            a3 = fmaf(c[i], w.w, a3);
        }
        float4 o; o.x = a0; o.y = a1; o.z = a2; o.w = a3;
        *reinterpret_cast<float4*>(&part[ks][cg * 4]) = o;
    }
    __syncthreads();
    {
        float y = 0.f;
        if (tid < 128) {
            y = bc[tid];
#pragma unroll
            for (int s = 0; s < 8; ++s) y += part[s][tid];
        }
        float s1 = (tid < 128) ? y : 0.f;
        float s2 = (tid < 128) ? y * y : 0.f;
        if (tid < 128) {
#pragma unroll
            for (int off = 32; off > 0; off >>= 1) {
                s1 += __shfl_down(s1, off);
                s2 += __shfl_down(s2, off);
            }
            if ((tid & 63) == 0) { red[(tid >> 6) * 2] = s1; red[(tid >> 6) * 2 + 1] = s2; }
        }
        __syncthreads();
        float mu = (red[0] + red[2]) * (1.f / 128.f);
        float ms = (red[1] + red[3]) * (1.f / 128.f);
        float var = ms - mu * mu;
        if (tid < 128) {
            float yv = (y - mu) * rsqrtf(var + EPS) * lncw[tid] + lncb[tid];
            vec[tid] = fmaxf(yv, 0.f);
        }
    }
    __syncthreads();

    // ---- layer B: vec @ Wf1, relu, LN ----
    {
        float c[16];
#pragma unroll
        for (int i = 0; i < 4; ++i) {
            float4 t = *reinterpret_cast<const float4*>(&vec[ks * 16 + i * 4]);
            c[i * 4 + 0] = t.x; c[i * 4 + 1] = t.y; c[i * 4 + 2] = t.z; c[i * 4 + 3] = t.w;
        }
        float a0 = 0.f, a1 = 0.f, a2 = 0.f, a3 = 0.f;
#pragma unroll
        for (int i = 0; i < 16; ++i) {
            const float4 w = *reinterpret_cast<const float4*>(&Wf1[(ks * 16 + i) * 128 + cg * 4]);
            a0 = fmaf(c[i], w.x, a0);
            a1 = fmaf(c[i], w.y, a1);
            a2 = fmaf(c[i], w.z, a2);
            a3 = fmaf(c[i], w.w, a3);
        }
        float4 o; o.x = a0; o.y = a1; o.z = a2; o.w = a3;
        *reinterpret_cast<float4*>(&part[ks][cg * 4]) = o;
    }
    __syncthreads();
    {
        float y = 0.f;
        if (tid < 128) {
            y = bf1[tid];
#pragma unroll
            for (int s = 0; s < 8; ++s) y += part[s][tid];
            y = fmaxf(y, 0.f);                 // relu BEFORE LN
        }
        float s1 = (tid < 128) ? y : 0.f;
        float s2 = (tid < 128) ? y * y : 0.f;
        if (tid < 128) {
#pragma unroll
            for (int off = 32; off > 0; off >>= 1) {
                s1 += __shfl_down(s1, off);
                s2 += __shfl_down(s2, off);
            }
            if ((tid & 63) == 0) { red[(tid >> 6) * 2] = s1; red[(tid >> 6) * 2 + 1] = s2; }
        }
        __syncthreads();
        float mu = (red[0] + red[2]) * (1.f / 128.f);
        float ms = (red[1] + red[3]) * (1.f / 128.f);
        float var = ms - mu * mu;
        if (tid < 128)
            vec[tid] = (y - mu) * rsqrtf(var + EPS) * ln1w[tid] + ln1b[tid];   // no relu
    }
    __syncthreads();

    // ---- layer C: vec @ Wf2 ----
    {
        float c[16];
#pragma unroll
        for (int i = 0; i < 4; ++i) {
            float4 t = *reinterpret_cast<const float4*>(&vec[ks * 16 + i * 4]);
            c[i * 4 + 0] = t.x; c[i * 4 + 1] = t.y; c[i * 4 + 2] = t.z; c[i * 4 + 3] = t.w;
        }
        float a0 = 0.f, a1 = 0.f, a2 = 0.f, a3 = 0.f;
#pragma unroll
        for (int i = 0; i < 16; ++i) {
            const float4 w = *reinterpret_cast<const float4*>(&Wf2[(ks * 16 + i) * 128 + cg * 4]);
            a0 = fmaf(c[i], w.x, a0);
            a1 = fmaf(c[i], w.y, a1);
            a2 = fmaf(c[i], w.z, a2);
            a3 = fmaf(c[i], w.w, a3);
        }
        float4 o; o.x = a0; o.y = a1; o.z = a2; o.w = a3;
        *reinterpret_cast<float4*>(&part[ks][cg * 4]) = o;
    }
    __syncthreads();
    if (tid < 128) {
        float y = bf2[tid];
#pragma unroll
        for (int s = 0; s < 8; ++s) y += part[s][tid];
        out[gi * 128 + tid] = y;
    }
}

// ---------- host launch ----------
extern "C" void kernel_launch(void* const* d_in, const int* in_sizes, int n_in,
                              void* d_out, int out_size, void* d_ws, size_t ws_size,
                              hipStream_t stream) {
    const float* x    = (const float*)d_in[0];
    const int*   ei   = (const int*)d_in[1];
    const int*   batch= (const int*)d_in[2];
    const int*   cell = (const int*)d_in[3];
    const float* W1   = (const float*)d_in[4];
    const float* b1   = (const float*)d_in[5];
    const float* W2   = (const float*)d_in[6];
    const float* b2   = (const float*)d_in[7];
    const float* emb  = (const float*)d_in[8];
    const float* Wc   = (const float*)d_in[9];
    const float* bc   = (const float*)d_in[10];
    const float* lncw = (const float*)d_in[11];
    const float* lncb = (const float*)d_in[12];
    const float* Wf1  = (const float*)d_in[13];
    const float* bf1  = (const float*)d_in[14];
    const float* ln1w = (const float*)d_in[15];
    const float* ln1b = (const float*)d_in[16];
    const float* Wf2  = (const float*)d_in[17];
    const float* bf2  = (const float*)d_in[18];
    float* out = (float*)d_out;

    char* ws = (char*)d_ws;
    size_t off = 0;
    auto alloc = [&](size_t bytes) { char* p = ws + off; off = (off + bytes + 255) & ~size_t(255); return p; };
    float*          dinv        = (float*)alloc(N_NODES * 4);
    int*            rowbeg      = (int*)  alloc(N_NODES * 4);
    unsigned short* deg         = (unsigned short*)alloc(N_NODES * 2);
    unsigned short* colidx      = (unsigned short*)alloc((size_t)NBUCK * BCAP * 2);
    int*            bucketCursor= (int*)  alloc(NBUCK * 4);
    unsigned int*   recbuf      = (unsigned int*)alloc((size_t)NBUCK * BCAP * 4);
    unsigned short* wt1         = (unsigned short*)alloc(128 * 128 * 2);
    unsigned short* wt2         = (unsigned short*)alloc(128 * 128 * 2);
    unsigned short* hs          = (unsigned short*)alloc((size_t)N_NODES * 128 * 2);
    unsigned short* h1          = (unsigned short*)alloc((size_t)N_NODES * 128 * 2);
    unsigned short* h2b         = (unsigned short*)alloc((size_t)N_NODES * 128 * 2);

    const int nbEdge = (NEDGE + EPB - 1) / EPB;        // 196
    const int nbGemm = (N_NODES + 127) / 128;          // 391
    const int nbAgg  = (N_NODES + 3) / 4;              // 12500

    // weight cast + cursor init (one dispatch, precedes scatter)
    wcast_kernel<<<dim3(64, 2), 256, 0, stream>>>(W1, W2, wt1, wt2, bucketCursor);

    // CSR build (2 kernels, dense atomic-cursor buckets)
    bucket_scatter_kernel<<<nbEdge, 256, 0, stream>>>(ei, bucketCursor, recbuf, NEDGE);
    bucket_csr_kernel<<<NBUCK, 256, 0, stream>>>(recbuf, bucketCursor, rowbeg, deg, dinv, colidx);

    // conv1
    gemm_mfma_kernel<true><<<nbGemm, 256, 0, stream>>>(x, wt1, dinv, hs, N_NODES);
    aggregate_kernel<<<nbAgg, 256, 0, stream>>>((const uint4*)hs, rowbeg, deg, colidx,
                                                dinv, b1, (uint4*)h1, N_NODES);
    // conv2
    gemm_mfma_kernel<false><<<nbGemm, 256, 0, stream>>>(h1, wt2, dinv, hs, N_NODES);
    aggregate_kernel<<<nbAgg, 256, 0, stream>>>((const uint4*)hs, rowbeg, deg, colidx,
                                                dinv, b2, (uint4*)h2b, N_NODES);
    // fused pool + tail
    tail_kernel<<<NGRAPH, 256, 0, stream>>>(h2b, batch, cell, emb, Wc, bc, lncw, lncb,
                                            Wf1, bf1, ln1w, ln1b, Wf2, bf2, out);
}

// Round 10
// 243.157 us; speedup vs baseline: 1.1541x; 1.0681x over previous
//
#include <hip/hip_runtime.h>

#define N_NODES 50000
#define NFEAT 128
#define NEDGE 800000
#define NGRAPH 512
#define NCE 64
#define EPS 1e-5f
#define NBUCK 196            // ceil(50000/256) buckets of 256 nodes
#define EPB 4096             // edges per bucket_scatter block
#define BCAP 6144            // fixed per-bucket capacity (avg 4082, sigma 64 -> +32 sigma)

typedef short s8v __attribute__((ext_vector_type(8)));
typedef float f4v __attribute__((ext_vector_type(4)));

// ---------- bf16 helpers (manual, bit-exact RNE) ----------
static __device__ __forceinline__ unsigned short f2bf(float f) {
    unsigned int u = __float_as_uint(f);
    unsigned int r = u + 0x7fffu + ((u >> 16) & 1u);
    return (unsigned short)(r >> 16);
}
static __device__ __forceinline__ float bf_lo(unsigned int packed) {
    return __uint_as_float(packed << 16);
}
static __device__ __forceinline__ float bf_hi(unsigned int packed) {
    return __uint_as_float(packed & 0xffff0000u);
}
static __device__ __forceinline__ float bf_us(unsigned short us) {
    return __uint_as_float(((unsigned int)us) << 16);
}

// ---------- 0. weight cast+transpose + cursor init ----------
__global__ __launch_bounds__(256) void wcast_kernel(
    const float* __restrict__ W1, const float* __restrict__ W2,
    unsigned short* __restrict__ WT1, unsigned short* __restrict__ WT2,
    int* __restrict__ bucketCursor)
{
    if (blockIdx.x == 0 && blockIdx.y == 0 && threadIdx.x < NBUCK)
        bucketCursor[threadIdx.x] = 0;
    const float* W = blockIdx.y ? W2 : W1;
    unsigned short* WT = blockIdx.y ? WT2 : WT1;
    int idx = blockIdx.x * 256 + threadIdx.x;   // 64 blocks x 256 = 16384
    int k = idx >> 7, n = idx & 127;
    WT[n * 128 + k] = f2bf(W[idx]);
}

// ---------- 1. bucket scatter: packed records, atomic-cursor dense buckets ----------
__global__ __launch_bounds__(256) void bucket_scatter_kernel(
    const int* __restrict__ ei, int* __restrict__ bucketCursor,
    unsigned int* __restrict__ recbuf, int E)
{
    __shared__ int hist[NBUCK];
    __shared__ int lbase[NBUCK];
    __shared__ int gbase[NBUCK];
    __shared__ int cur[NBUCK];
    __shared__ int scanbuf[256];
    __shared__ unsigned int staging[EPB];
    int tid = threadIdx.x;
    if (tid < NBUCK) { hist[tid] = 0; cur[tid] = 0; }
    __syncthreads();

    unsigned int rec[EPB / 256];
    int e0 = blockIdx.x * EPB + tid;
#pragma unroll
    for (int i = 0; i < EPB / 256; ++i) {
        int e = e0 + i * 256;
        if (e < E) {
            unsigned int sv = (unsigned)ei[e];
            unsigned int dv = (unsigned)ei[E + e];
            rec[i] = sv | (dv << 16);
            atomicAdd(&hist[dv >> 8], 1);
        } else {
            rec[i] = 0xffffffffu;
        }
    }
    __syncthreads();
    int v = (tid < NBUCK) ? hist[tid] : 0;
    scanbuf[tid] = v; __syncthreads();
    for (int off = 1; off < 256; off <<= 1) {
        int t = (tid >= off) ? scanbuf[tid - off] : 0;
        __syncthreads();
        scanbuf[tid] += t;
        __syncthreads();
    }
    if (tid < NBUCK) lbase[tid] = scanbuf[tid] - v;
    int total = scanbuf[255];
    if (tid < NBUCK) gbase[tid] = (v > 0) ? atomicAdd(&bucketCursor[tid], v) : 0;
    __syncthreads();
#pragma unroll
    for (int i = 0; i < EPB / 256; ++i) {
        if (rec[i] != 0xffffffffu) {
            int b = rec[i] >> 24;       // dst >> 8
            int loc = atomicAdd(&cur[b], 1);
            staging[lbase[b] + loc] = rec[i];
        }
    }
    __syncthreads();
    for (int s = tid; s < total; s += 256) {
        unsigned int r = staging[s];
        int b = r >> 24;
        int pos = gbase[b] + (s - lbase[b]);
        if (pos < BCAP) recbuf[(size_t)b * BCAP + pos] = r;
    }
}

// ---------- 2. per-bucket CSR finalize (dense buckets) ----------
__global__ __launch_bounds__(256) void bucket_csr_kernel(
    const unsigned int* __restrict__ recbuf, const int* __restrict__ bucketCursor,
    int* __restrict__ rowbeg, unsigned short* __restrict__ deg,
    float* __restrict__ dinv, unsigned short* __restrict__ colidx)
{
    __shared__ int cnt[256];
    __shared__ int cur[256];
    __shared__ int scanbuf[256];
    __shared__ unsigned short stage[BCAP];
    int b = blockIdx.x, tid = threadIdx.x;
    int base = b * BCAP;
    int len = bucketCursor[b]; if (len > BCAP) len = BCAP;
    cnt[tid] = 0;
    __syncthreads();
    for (int s = tid; s < len; s += 256) {
        unsigned int r = recbuf[base + s];
        atomicAdd(&cnt[(r >> 16) & 255], 1);
    }
    __syncthreads();
    int v = cnt[tid];
    scanbuf[tid] = v; __syncthreads();
    for (int off = 1; off < 256; off <<= 1) {
        int t = (tid >= off) ? scanbuf[tid - off] : 0;
        __syncthreads();
        scanbuf[tid] += t;
        __syncthreads();
    }
    int excl = scanbuf[tid] - v;
    int node = b * 256 + tid;
    if (node < N_NODES) {
        rowbeg[node] = base + excl;
        deg[node] = (unsigned short)v;
        dinv[node] = rsqrtf((float)v + 1.0f);
    }
    cur[tid] = excl;
    __syncthreads();
    for (int s = tid; s < len; s += 256) {
        unsigned int r = recbuf[base + s];
        int pos = atomicAdd(&cur[(r >> 16) & 255], 1);
        stage[pos] = (unsigned short)(r & 0xffffu);
    }
    __syncthreads();
    for (int s = tid; s < len; s += 256) colidx[base + s] = stage[s];
}

// ---------- MFMA GEMM: HS[r][c] = bf16( (A @ W)[r][c] * dinv[r] ) ----------
template<bool FP32IN>
__global__ __launch_bounds__(256) void gemm_mfma_kernel(
    const void* __restrict__ Ain, const unsigned short* __restrict__ WTg,
    const float* __restrict__ dinv, unsigned short* __restrict__ HS, int nrows)
{
    __shared__ unsigned short as[128 * 128];   // 32 KB; reused for result staging
    __shared__ unsigned short wt[128 * 128];   // 32 KB
    const int tid = threadIdx.x;
    const int row0 = blockIdx.x * 128;

    {
        const uint4* src = reinterpret_cast<const uint4*>(WTg);
        uint4* dst = reinterpret_cast<uint4*>(wt);
#pragma unroll
        for (int i = 0; i < 8; ++i) dst[tid + i * 256] = src[tid + i * 256];
    }
    if (FP32IN) {
        const float* X = (const float*)Ain;
#pragma unroll
        for (int i = 0; i < 16; ++i) {
            int f = tid + i * 256;
            int r = f >> 5, c4 = f & 31;
            int rr = row0 + r; if (rr >= nrows) rr = nrows - 1;
            float4 v = *reinterpret_cast<const float4*>(&X[rr * 128 + c4 * 4]);
            ushort4 o;
            o.x = f2bf(v.x); o.y = f2bf(v.y); o.z = f2bf(v.z); o.w = f2bf(v.w);
            *reinterpret_cast<ushort4*>(&as[r * 128 + c4 * 4]) = o;
        }
    } else {
        const unsigned short* X = (const unsigned short*)Ain;
#pragma unroll
        for (int i = 0; i < 8; ++i) {
            int f = tid + i * 256;
            int r = f >> 4, c8 = f & 15;
            int rr = row0 + r; if (rr >= nrows) rr = nrows - 1;
            *reinterpret_cast<uint4*>(&as[r * 128 + c8 * 8]) =
                *reinterpret_cast<const uint4*>(&X[rr * 128 + c8 * 8]);
        }
    }
    __syncthreads();

    const int w = tid >> 6;
    const int lane = tid & 63;
    const int quad = lane >> 4;
    const int col0 = lane & 15;

    s8v afr[2][4];
#pragma unroll
    for (int rt = 0; rt < 2; ++rt)
#pragma unroll
        for (int kt = 0; kt < 4; ++kt)
            afr[rt][kt] = *reinterpret_cast<const s8v*>(
                &as[(w * 32 + rt * 16 + col0) * 128 + kt * 32 + quad * 8]);

    f4v acc[2][8];
#pragma unroll
    for (int rt = 0; rt < 2; ++rt)
#pragma unroll
        for (int nt = 0; nt < 8; ++nt)
            acc[rt][nt] = (f4v){0.f, 0.f, 0.f, 0.f};

#pragma unroll
    for (int nt = 0; nt < 8; ++nt) {
        s8v bfr[4];
#pragma unroll
        for (int kt = 0; kt < 4; ++kt)
            bfr[kt] = *reinterpret_cast<const s8v*>(
                &wt[(nt * 16 + col0) * 128 + kt * 32 + quad * 8]);
#pragma unroll
        for (int rt = 0; rt < 2; ++rt)
#pragma unroll
            for (int kt = 0; kt < 4; ++kt)
                acc[rt][nt] = __builtin_amdgcn_mfma_f32_16x16x32_bf16(
                    afr[rt][kt], bfr[kt], acc[rt][nt], 0, 0, 0);
    }

    float dv[2][4];
#pragma unroll
    for (int rt = 0; rt < 2; ++rt)
#pragma unroll
        for (int reg = 0; reg < 4; ++reg) {
            int r = row0 + w * 32 + rt * 16 + quad * 4 + reg;
            dv[rt][reg] = (r < nrows) ? dinv[r] : 0.f;
        }

#pragma unroll
    for (int rt = 0; rt < 2; ++rt)
#pragma unroll
        for (int nt = 0; nt < 8; ++nt)
#pragma unroll
            for (int reg = 0; reg < 4; ++reg) {
                int rl = w * 32 + rt * 16 + quad * 4 + reg;
                as[rl * 128 + nt * 16 + col0] = f2bf(acc[rt][nt][reg] * dv[rt][reg]);
            }
    __syncthreads();
#pragma unroll
    for (int i = 0; i < 8; ++i) {
        int f = tid + i * 256;
        int r = f >> 4, c8 = f & 15;
        if (row0 + r < nrows)
            *reinterpret_cast<uint4*>(&HS[(size_t)(row0 + r) * 128 + c8 * 8]) =
                *reinterpret_cast<const uint4*>(&as[r * 128 + c8 * 8]);
    }
}

// ---------- aggregation v3: one wave per node, PAIRED row gathers ----------
// lanes 0-31 load row u[2j], lanes 32-63 load row u[2j+1]; 8 B/lane (uint2).
// Self row folded in as neighbor 0. Cross-half combine via shfl_xor(32).
__global__ __launch_bounds__(256) void aggregate_kernel(
    const uint2* __restrict__ H2,                 // [N][32] uint2 (bf16x4)
    const int* __restrict__ rowbeg, const unsigned short* __restrict__ deg,
    const unsigned short* __restrict__ colidx,
    const float* __restrict__ dinv, const float* __restrict__ bias,
    uint2* __restrict__ OUT, int n)
{
    int wid = (blockIdx.x * blockDim.x + threadIdx.x) >> 6;
    int lane = threadIdx.x & 63;
    if (wid >= n) return;
    const int half = lane >> 5;
    const int sub = lane & 31;
    int beg = rowbeg[wid];
    int cnt = (int)deg[wid] + 1;                  // + self
    float s0 = 0.f, s1 = 0.f, s2 = 0.f, s3 = 0.f; // bank A
    float r0 = 0.f, r1 = 0.f, r2 = 0.f, r3 = 0.f; // bank B
    for (int base = 0; base < cnt; base += 64) {
        int m = cnt - base; if (m > 64) m = 64;
        int p = base + lane;
        int idx = 0;
        if (lane < m) idx = (p == 0) ? wid : (int)colidx[beg + p - 1];
        int j = 0;
        for (; j + 16 <= m; j += 16) {            // 8 pair-loads = 16 rows in flight
            uint2 t[8];
#pragma unroll
            for (int q = 0; q < 8; ++q) {
                int u = __shfl(idx, j + q * 2 + half);
                t[q] = H2[(size_t)u * 32 + sub];
            }
#pragma unroll
            for (int q = 0; q < 8; q += 2) {
                s0 += bf_lo(t[q].x); s1 += bf_hi(t[q].x);
                s2 += bf_lo(t[q].y); s3 += bf_hi(t[q].y);
                r0 += bf_lo(t[q + 1].x); r1 += bf_hi(t[q + 1].x);
                r2 += bf_lo(t[q + 1].y); r3 += bf_hi(t[q + 1].y);
            }
        }
        for (; j + 4 <= m; j += 4) {              // 2 pair-loads
            int ua = __shfl(idx, j + half);
            int ub = __shfl(idx, j + 2 + half);
            uint2 ta = H2[(size_t)ua * 32 + sub];
            uint2 tb = H2[(size_t)ub * 32 + sub];
            s0 += bf_lo(ta.x); s1 += bf_hi(ta.x);
            s2 += bf_lo(ta.y); s3 += bf_hi(ta.y);
            r0 += bf_lo(tb.x); r1 += bf_hi(tb.x);
            r2 += bf_lo(tb.y); r3 += bf_hi(tb.y);
        }
        if (j + 2 <= m) {                         // 1 pair-load
            int u = __shfl(idx, j + half);
            uint2 t = H2[(size_t)u * 32 + sub];
            s0 += bf_lo(t.x); s1 += bf_hi(t.x);
            s2 += bf_lo(t.y); s3 += bf_hi(t.y);
            j += 2;
        }
        if (j < m) {                              // odd singleton: half 0 only
            int u = __shfl(idx, j);
            uint2 t; t.x = 0u; t.y = 0u;
            if (half == 0) t = H2[(size_t)u * 32 + sub];
            s0 += bf_lo(t.x); s1 += bf_hi(t.x);
            s2 += bf_lo(t.y); s3 += bf_hi(t.y);
        }
    }
    s0 += r0; s1 += r1; s2 += r2; s3 += r3;
    s0 += __shfl_xor(s0, 32);
    s1 += __shfl_xor(s1, 32);
    s2 += __shfl_xor(s2, 32);
    s3 += __shfl_xor(s3, 32);
    if (half == 0) {
        float sc = dinv[wid];
        float4 bv = *reinterpret_cast<const float4*>(&bias[sub * 4]);
        float o0 = fmaxf(fmaf(s0, sc, bv.x), 0.f);
        float o1 = fmaxf(fmaf(s1, sc, bv.y), 0.f);
        float o2 = fmaxf(fmaf(s2, sc, bv.z), 0.f);
        float o3 = fmaxf(fmaf(s3, sc, bv.w), 0.f);
        uint2 o;
        o.x = (unsigned int)f2bf(o0) | ((unsigned int)f2bf(o1) << 16);
        o.y = (unsigned int)f2bf(o2) | ((unsigned int)f2bf(o3) << 16);
        OUT[(size_t)wid * 32 + sub] = o;
    }
}

// ---------- fused pool + tail ----------
__global__ __launch_bounds__(256) void tail_kernel(
    const unsigned short* __restrict__ h2b, const int* __restrict__ batch,
    const int* __restrict__ cell, const float* __restrict__ emb,
    const float* __restrict__ Wc, const float* __restrict__ bc,
    const float* __restrict__ lncw, const float* __restrict__ lncb,
    const float* __restrict__ Wf1, const float* __restrict__ bf1,
    const float* __restrict__ ln1w, const float* __restrict__ ln1b,
    const float* __restrict__ Wf2, const float* __restrict__ bf2,
    float* __restrict__ out)
{
    __shared__ __align__(16) float comb[192];
    __shared__ __align__(16) float part[8][132];
    __shared__ float red[4];
    __shared__ __align__(16) float vec[128];
    const int gi = blockIdx.x;
    const int tid = threadIdx.x;
    const int cg = tid & 31;
    const int ks = tid >> 5;

    int lo = 0, hi = N_NODES;
    while (lo < hi) { int mid = (lo + hi) >> 1; if (batch[mid] < gi) lo = mid + 1; else hi = mid; }
    int lo2 = lo, hi2 = N_NODES;
    while (lo2 < hi2) { int mid = (lo2 + hi2) >> 1; if (batch[mid] < gi + 1) lo2 = mid + 1; else hi2 = mid; }

    {
        int half = tid >> 7;
        int j = tid & 127;
        float acc = 0.f;
        for (int v = lo + half; v < lo2; v += 2)
            acc += bf_us(h2b[(size_t)v * 128 + j]);
        part[half][j] = acc;
    }
    __syncthreads();
    if (tid < 128) comb[tid] = part[0][tid] + part[1][tid];
    else if (tid < 192) comb[tid] = emb[cell[gi] * 64 + (tid - 128)];
    __syncthreads();

    // ---- layer A: comb @ Wc ----
    {
        float c[24];
#pragma unroll
        for (int i = 0; i < 6; ++i) {
            float4 t = *reinterpret_cast<const float4*>(&comb[ks * 24 + i * 4]);
            c[i * 4 + 0] = t.x; c[i * 4 + 1] = t.y; c[i * 4 + 2] = t.z; c[i * 4 + 3] = t.w;
        }
        float a0 = 0.f, a1 = 0.f, a2 = 0.f, a3 = 0.f;
#pragma unroll
        for (int i = 0; i < 24; ++i) {
            const float4 w = *reinterpret_cast<const float4*>(&Wc[(ks * 24 + i) * 128 + cg * 4]);
            a0 = fmaf(c[i], w.x, a0);
            a1 = fmaf(c[i], w.y, a1);
            a2 = fmaf(c[i], w.z, a2);
            a3 = fmaf(c[i], w.w, a3);
        }
        float4 o; o.x = a0; o.y = a1; o.z = a2; o.w = a3;
        *reinterpret_cast<float4*>(&part[ks][cg * 4]) = o;
    }
    __syncthreads();
    {
        float y = 0.f;
        if (tid < 128) {
            y = bc[tid];
#pragma unroll
            for (int s = 0; s < 8; ++s) y += part[s][tid];
        }
        float s1 = (tid < 128) ? y : 0.f;
        float s2 = (tid < 128) ? y * y : 0.f;
        if (tid < 128) {
#pragma unroll
            for (int off = 32; off > 0; off >>= 1) {
                s1 += __shfl_down(s1, off);
                s2 += __shfl_down(s2, off);
            }
            if ((tid & 63) == 0) { red[(tid >> 6) * 2] = s1; red[(tid >> 6) * 2 + 1] = s2; }
        }
        __syncthreads();
        float mu = (red[0] + red[2]) * (1.f / 128.f);
        float ms = (red[1] + red[3]) * (1.f / 128.f);
        float var = ms - mu * mu;
        if (tid < 128) {
            float yv = (y - mu) * rsqrtf(var + EPS) * lncw[tid] + lncb[tid];
            vec[tid] = fmaxf(yv, 0.f);
        }
    }
    __syncthreads();

    // ---- layer B: vec @ Wf1, relu, LN ----
    {
        float c[16];
#pragma unroll
        for (int i = 0; i < 4; ++i) {
            float4 t = *reinterpret_cast<const float4*>(&vec[ks * 16 + i * 4]);
            c[i * 4 + 0] = t.x; c[i * 4 + 1] = t.y; c[i * 4 + 2] = t.z; c[i * 4 + 3] = t.w;
        }
        float a0 = 0.f, a1 = 0.f, a2 = 0.f, a3 = 0.f;
#pragma unroll
        for (int i = 0; i < 16; ++i) {
            const float4 w = *reinterpret_cast<const float4*>(&Wf1[(ks * 16 + i) * 128 + cg * 4]);
            a0 = fmaf(c[i], w.x, a0);
            a1 = fmaf(c[i], w.y, a1);
            a2 = fmaf(c[i], w.z, a2);
            a3 = fmaf(c[i], w.w, a3);
        }
        float4 o; o.x = a0; o.y = a1; o.z = a2; o.w = a3;
        *reinterpret_cast<float4*>(&part[ks][cg * 4]) = o;
    }
    __syncthreads();
    {
        float y = 0.f;
        if (tid < 128) {
            y = bf1[tid];
#pragma unroll
            for (int s = 0; s < 8; ++s) y += part[s][tid];
            y = fmaxf(y, 0.f);                 // relu BEFORE LN
        }
        float s1 = (tid < 128) ? y : 0.f;
        float s2 = (tid < 128) ? y * y : 0.f;
        if (tid < 128) {
#pragma unroll
            for (int off = 32; off > 0; off >>= 1) {
                s1 += __shfl_down(s1, off);
                s2 += __shfl_down(s2, off);
            }
            if ((tid & 63) == 0) { red[(tid >> 6) * 2] = s1; red[(tid >> 6) * 2 + 1] = s2; }
        }
        __syncthreads();
        float mu = (red[0] + red[2]) * (1.f / 128.f);
        float ms = (red[1] + red[3]) * (1.f / 128.f);
        float var = ms - mu * mu;
        if (tid < 128)
            vec[tid] = (y - mu) * rsqrtf(var + EPS) * ln1w[tid] + ln1b[tid];   // no relu
    }
    __syncthreads();

    // ---- layer C: vec @ Wf2 ----
    {
        float c[16];
#pragma unroll
        for (int i = 0; i < 4; ++i) {
            float4 t = *reinterpret_cast<const float4*>(&vec[ks * 16 + i * 4]);
            c[i * 4 + 0] = t.x; c[i * 4 + 1] = t.y; c[i * 4 + 2] = t.z; c[i * 4 + 3] = t.w;
        }
        float a0 = 0.f, a1 = 0.f, a2 = 0.f, a3 = 0.f;
#pragma unroll
        for (int i = 0; i < 16; ++i) {
            const float4 w = *reinterpret_cast<const float4*>(&Wf2[(ks * 16 + i) * 128 + cg * 4]);
            a0 = fmaf(c[i], w.x, a0);
            a1 = fmaf(c[i], w.y, a1);
            a2 = fmaf(c[i], w.z, a2);
            a3 = fmaf(c[i], w.w, a3);
        }
        float4 o; o.x = a0; o.y = a1; o.z = a2; o.w = a3;
        *reinterpret_cast<float4*>(&part[ks][cg * 4]) = o;
    }
    __syncthreads();
    if (tid < 128) {
        float y = bf2[tid];
#pragma unroll
        for (int s = 0; s < 8; ++s) y += part[s][tid];
        out[gi * 128 + tid] = y;
    }
}

// ---------- host launch ----------
extern "C" void kernel_launch(void* const* d_in, const int* in_sizes, int n_in,
                              void* d_out, int out_size, void* d_ws, size_t ws_size,
                              hipStream_t stream) {
    const float* x    = (const float*)d_in[0];
    const int*   ei   = (const int*)d_in[1];
    const int*   batch= (const int*)d_in[2];
    const int*   cell = (const int*)d_in[3];
    const float* W1   = (const float*)d_in[4];
    const float* b1   = (const float*)d_in[5];
    const float* W2   = (const float*)d_in[6];
    const float* b2   = (const float*)d_in[7];
    const float* emb  = (const float*)d_in[8];
    const float* Wc   = (const float*)d_in[9];
    const float* bc   = (const float*)d_in[10];
    const float* lncw = (const float*)d_in[11];
    const float* lncb = (const float*)d_in[12];
    const float* Wf1  = (const float*)d_in[13];
    const float* bf1  = (const float*)d_in[14];
    const float* ln1w = (const float*)d_in[15];
    const float* ln1b = (const float*)d_in[16];
    const float* Wf2  = (const float*)d_in[17];
    const float* bf2  = (const float*)d_in[18];
    float* out = (float*)d_out;

    char* ws = (char*)d_ws;
    size_t off = 0;
    auto alloc = [&](size_t bytes) { char* p = ws + off; off = (off + bytes + 255) & ~size_t(255); return p; };
    float*          dinv        = (float*)alloc(N_NODES * 4);
    int*            rowbeg      = (int*)  alloc(N_NODES * 4);
    unsigned short* deg         = (unsigned short*)alloc(N_NODES * 2);
    unsigned short* colidx      = (unsigned short*)alloc((size_t)NBUCK * BCAP * 2);
    int*            bucketCursor= (int*)  alloc(NBUCK * 4);
    unsigned int*   recbuf      = (unsigned int*)alloc((size_t)NBUCK * BCAP * 4);
    unsigned short* wt1         = (unsigned short*)alloc(128 * 128 * 2);
    unsigned short* wt2         = (unsigned short*)alloc(128 * 128 * 2);
    unsigned short* hs          = (unsigned short*)alloc((size_t)N_NODES * 128 * 2);
    unsigned short* h1          = (unsigned short*)alloc((size_t)N_NODES * 128 * 2);
    unsigned short* h2b         = (unsigned short*)alloc((size_t)N_NODES * 128 * 2);

    const int nbEdge = (NEDGE + EPB - 1) / EPB;        // 196
    const int nbGemm = (N_NODES + 127) / 128;          // 391
    const int nbAgg  = (N_NODES + 3) / 4;              // 12500

    // weight cast + cursor init (one dispatch, precedes scatter)
    wcast_kernel<<<dim3(64, 2), 256, 0, stream>>>(W1, W2, wt1, wt2, bucketCursor);

    // CSR build (2 kernels, dense atomic-cursor buckets)
    bucket_scatter_kernel<<<nbEdge, 256, 0, stream>>>(ei, bucketCursor, recbuf, NEDGE);
    bucket_csr_kernel<<<NBUCK, 256, 0, stream>>>(recbuf, bucketCursor, rowbeg, deg, dinv, colidx);

    // conv1
    gemm_mfma_kernel<true><<<nbGemm, 256, 0, stream>>>(x, wt1, dinv, hs, N_NODES);
    aggregate_kernel<<<nbAgg, 256, 0, stream>>>((const uint2*)hs, rowbeg, deg, colidx,
                                                dinv, b1, (uint2*)h1, N_NODES);
    // conv2
    gemm_mfma_kernel<false><<<nbGemm, 256, 0, stream>>>(h1, wt2, dinv, hs, N_NODES);
    aggregate_kernel<<<nbAgg, 256, 0, stream>>>((const uint2*)hs, rowbeg, deg, colidx,
                                                dinv, b2, (uint2*)h2b, N_NODES);
    // fused pool + tail
    tail_kernel<<<NGRAPH, 256, 0, stream>>>(h2b, batch, cell, emb, Wc, bc, lncw, lncb,
                                            Wf1, bf1, ln1w, ln1b, Wf2, bf2, out);
}